// Round 9
// baseline (127.843 us; speedup 1.0000x reference)
//
#include <hip/hip_runtime.h>

typedef __attribute__((ext_vector_type(8))) short short8;
typedef __attribute__((ext_vector_type(4))) float f32x4;

#define MFMA(a, b, c) __builtin_amdgcn_mfma_f32_16x16x32_bf16((a), (b), (c), 0, 0, 0)

#define S_LEN 1024
#define DM 1024
#define NHEADS 16
#define HD 64
#define NBH 64          // B * NHEADS = 4 * 16
#define MAXPOS 4096

__device__ __forceinline__ ushort f2bf(float f) {
    unsigned u = __builtin_bit_cast(unsigned, f);
    u += 0x7fffu + ((u >> 16) & 1u);
    return (ushort)(u >> 16);
}
__device__ __forceinline__ float bf2f(ushort h) {
    return __builtin_bit_cast(float, (unsigned)h << 16);
}

// async global->LDS, 16B per lane. LDS dest must be base + lane*16 linear.
__device__ __forceinline__ void gload16(const ushort* g, ushort* l) {
    __builtin_amdgcn_global_load_lds(
        (const __attribute__((address_space(1))) unsigned int*)g,
        (__attribute__((address_space(3))) unsigned int*)l, 16, 0, 0);
}

// ---------------- RoPE table: tab[p][i] = {cos, sin}, p<4096, i<32 ----------
__global__ __launch_bounds__(256) void k_build_tab(float* __restrict__ tab) {
    int id = blockIdx.x * 256 + threadIdx.x;      // 4096*32 entries
    int p = id >> 5, i = id & 31;
    float inv = powf(10000.f, -(float)(2 * i) / 64.f);
    float t = (float)p * inv;
    float s, c;
    sincosf(t, &s, &c);
    tab[2 * id] = c;
    tab[2 * id + 1] = s;
}

// ---------------- fp32 -> bf16 conversion, all three tensors, one launch ----
__global__ __launch_bounds__(256) void k_cvt3(const float4* __restrict__ hs,
                                              const float4* __restrict__ wqkv,
                                              const float4* __restrict__ wout,
                                              ushort4* __restrict__ hsB,
                                              ushort4* __restrict__ wqkvB,
                                              ushort4* __restrict__ woutB) {
    int id = blockIdx.x * 256 + threadIdx.x;
    const float4* src;
    ushort4* dst;
    int off;
    if (id < 1048576)      { src = hs;   dst = hsB;   off = id; }
    else if (id < 1835008) { src = wqkv; dst = wqkvB; off = id - 1048576; }
    else                   { src = wout; dst = woutB; off = id - 1835008; }
    float4 v = src[off];
    ushort4 o;
    o.x = f2bf(v.x); o.y = f2bf(v.y); o.z = f2bf(v.z); o.w = f2bf(v.w);
    dst[off] = o;
}

// ---------------- bf16 GEMM, C = A @ B^T, 128x128 tile ----------------------
// Counted-vmcnt ring (T3/T4): BK=32, 3 LDS bufs, 2 K-tiles ahead, vmcnt(4),
// raw s_barrier; compiler-scheduled ds_read/MFMA interleave. T2 XOR swizzle.
// MODE 0: f32 C. MODE 1: fused RoPE/head-split/V-transpose epilogue.
template <int MODE>
__global__ __launch_bounds__(256, 3) void k_gemm(
    const ushort* __restrict__ A, const ushort* __restrict__ BT,
    float* __restrict__ Cf,
    const int* __restrict__ pos, const float* __restrict__ tab,
    ushort* __restrict__ Qh, ushort* __restrict__ Kh, ushort* __restrict__ Vt,
    int M, int N, int K, int nbx) {
    __shared__ __align__(16) ushort SH[3 * 8192];   // 48 KB
    const int tid = threadIdx.x;
    const int lane = tid & 63, wave = tid >> 6;
    const int wr = wave >> 1, wc = wave & 1;
    const int l15 = lane & 15, lhi = lane >> 4;
    const int nby = gridDim.x / nbx;
    const int xcd = blockIdx.x & 7, idx = blockIdx.x >> 3;
    const int Creg = nbx >> 1, Rreg = nby >> 2;
    const int by = (xcd >> 1) * Rreg + idx / Creg;
    const int bx = (xcd & 1) * Creg + idx % Creg;
    const int m0 = by << 7, n0 = bx << 7;

    const int srow = tid >> 2;                                        // 0..63
    const int scol = (((tid >> 2) & 3) ^ ((tid >> 4) & 3) ^ (tid & 3)) << 3;
    const int fcol = ((lhi ^ ((l15 & 3) ^ ((l15 >> 2) & 3)))) << 3;

    f32x4 acc[4][4];
#pragma unroll
    for (int i = 0; i < 4; ++i)
#pragma unroll
        for (int j = 0; j < 4; ++j) acc[i][j] = 0;

#define STAGE(bs, kb)                                                           \
    do {                                                                        \
        ushort* bb = SH + (bs) * 8192;                                          \
        gload16(&A[(size_t)(m0 + srow) * K + (kb) + scol], bb + tid * 8);       \
        gload16(&A[(size_t)(m0 + 64 + srow) * K + (kb) + scol],                 \
                bb + 2048 + tid * 8);                                           \
        gload16(&BT[(size_t)(n0 + srow) * K + (kb) + scol],                     \
                bb + 4096 + tid * 8);                                           \
        gload16(&BT[(size_t)(n0 + 64 + srow) * K + (kb) + scol],                \
                bb + 6144 + tid * 8);                                           \
    } while (0)

    const int nk = K >> 5;              // BK = 32
    STAGE(0, 0);
    STAGE(1, 32);
    int bi = 0;
    for (int t = 0; t < nk; ++t) {
        if (t + 1 < nk) {
            asm volatile("s_waitcnt vmcnt(4)" ::: "memory");
        } else {
            asm volatile("s_waitcnt vmcnt(0)" ::: "memory");
        }
        __builtin_amdgcn_s_barrier();
        __builtin_amdgcn_sched_barrier(0);   // pin: nothing crosses the publish point
        if (t + 2 < nk) {
            int bs = bi + 2;
            if (bs >= 3) bs -= 3;
            STAGE(bs, (t + 2) << 5);
        }
        const ushort* bufA = SH + bi * 8192;
        const ushort* bufB = bufA + 4096;
        short8 a[4], b[4];
#pragma unroll
        for (int fm = 0; fm < 4; ++fm)
            a[fm] = *(const short8*)&bufA[(wr * 64 + fm * 16 + l15) * 32 + fcol];
#pragma unroll
        for (int fn = 0; fn < 4; ++fn)
            b[fn] = *(const short8*)&bufB[(wc * 64 + fn * 16 + l15) * 32 + fcol];
#pragma unroll
        for (int fm = 0; fm < 4; ++fm)
#pragma unroll
            for (int fn = 0; fn < 4; ++fn)
                acc[fm][fn] = MFMA(a[fm], b[fn], acc[fm][fn]);
        bi = (bi == 2) ? 0 : bi + 1;
    }
#undef STAGE
    __syncthreads();                    // LDS reuse (V-transpose bounce) safety

    if (MODE == 0) {
#pragma unroll
        for (int fm = 0; fm < 4; ++fm)
#pragma unroll
            for (int fn = 0; fn < 4; ++fn)
#pragma unroll
                for (int i = 0; i < 4; ++i) {
                    int row = m0 + wr * 64 + fm * 16 + lhi * 4 + i;
                    int col = n0 + wc * 64 + fn * 16 + l15;
                    Cf[(size_t)row * N + col] = acc[fm][fn][i];
                }
    } else {
        const int sec = n0 >> 10;                       // 0=q, 1=k, 2=v
        if (sec < 2) {
            ushort* dstb = sec == 0 ? Qh : Kh;
            const float qs = sec == 0 ? 0.125f : 1.0f;
#pragma unroll
            for (int fm = 0; fm < 4; ++fm)
#pragma unroll
                for (int i = 0; i < 4; ++i) {
                    const int row = m0 + wr * 64 + fm * 16 + lhi * 4 + i;
                    const int b = row >> 10, s = row & 1023;
                    int p = pos[s];
                    p = p < 0 ? 0 : (p > MAXPOS - 1 ? MAXPOS - 1 : p);
#pragma unroll
                    for (int fn = 0; fn < 4; ++fn) {
                        const int col = n0 + wc * 64 + fn * 16 + l15;
                        const int cw = col & 1023;
                        const int h = cw >> 6, d = cw & 63;
                        const float2 cs = *(const float2*)&tab[((size_t)p * 32 + (d >> 1)) * 2];
                        const float v = acc[fm][fn][i];
                        const float pr = __shfl_xor(v, 1);
                        const float o = ((d & 1) ? (v * cs.x + pr * cs.y)
                                                 : (v * cs.x - pr * cs.y)) * qs;
                        const float op = __shfl_xor(o, 1);   // partner's output
                        if (!(l15 & 1)) {                    // even lane stores the pair
                            const unsigned pk = (unsigned)f2bf(o) | ((unsigned)f2bf(op) << 16);
                            *(unsigned*)&dstb[((size_t)((b * 16 + h) * 1024 + s)) * 64 + d] = pk;
                        }
                    }
                }
        } else {
            // V: transpose via LDS bounce (reuse staging buffer), [128][132] pad
            ushort (*T)[132] = (ushort(*)[132]) & SH[0];
#pragma unroll
            for (int fm = 0; fm < 4; ++fm)
#pragma unroll
                for (int fn = 0; fn < 4; ++fn)
#pragma unroll
                    for (int i = 0; i < 4; ++i)
                        T[wr * 64 + fm * 16 + lhi * 4 + i][wc * 64 + fn * 16 + l15] =
                            f2bf(acc[fm][fn][i]);
            __syncthreads();
            const int b = m0 >> 10, s0 = m0 & 1023;
            const int dd = tid & 127, scg = tid >> 7;   // dd: 2 heads x 64 dims
            const int hv = ((n0 & 1023) >> 6) + (dd >> 6);
            const int d = dd & 63;
            ushort* dst = Vt + ((size_t)(b * 16 + hv) * 64 + d) * S_LEN + s0;
#pragma unroll
            for (int j = 0; j < 8; ++j) {
                const int ch = scg * 8 + j;             // 16 chunks of 8 seq
                __align__(16) ushort tmp[8];
#pragma unroll
                for (int e = 0; e < 8; ++e) tmp[e] = T[ch * 8 + e][dd];
                *(uint4*)&dst[ch * 8] = *(uint4*)tmp;
            }
        }
    }
}

// ---------------- DIAGNOSTIC: K-loop without in-loop staging ----------------
// Same grid/occupancy/swizzle/loop as k_gemm, but no in-loop gload/vmcnt:
// isolates the {barrier + ds_read + MFMA} phase cost. Writes to scratch only.
__global__ __launch_bounds__(256, 3) void k_diag_nostage(
    const ushort* __restrict__ A, const ushort* __restrict__ BT,
    float* __restrict__ dump) {
    __shared__ __align__(16) ushort SH[3 * 8192];
    const int K = 1024, nbx = 24;
    const int tid = threadIdx.x;
    const int lane = tid & 63, wave = tid >> 6;
    const int wr = wave >> 1, wc = wave & 1;
    const int l15 = lane & 15, lhi = lane >> 4;
    const int nby = gridDim.x / nbx;
    const int xcd = blockIdx.x & 7, idx = blockIdx.x >> 3;
    const int Creg = nbx >> 1, Rreg = nby >> 2;
    const int by = (xcd >> 1) * Rreg + idx / Creg;
    const int bx = (xcd & 1) * Creg + idx % Creg;
    const int m0 = by << 7, n0 = bx << 7;
    const int srow = tid >> 2;
    const int scol = (((tid >> 2) & 3) ^ ((tid >> 4) & 3) ^ (tid & 3)) << 3;
    const int fcol = ((lhi ^ ((l15 & 3) ^ ((l15 >> 2) & 3)))) << 3;

    f32x4 acc[4][4];
#pragma unroll
    for (int i = 0; i < 4; ++i)
#pragma unroll
        for (int j = 0; j < 4; ++j) acc[i][j] = 0;

#define DSTAGE(bs, kb)                                                          \
    do {                                                                        \
        ushort* bb = SH + (bs) * 8192;                                          \
        gload16(&A[(size_t)(m0 + srow) * K + (kb) + scol], bb + tid * 8);       \
        gload16(&A[(size_t)(m0 + 64 + srow) * K + (kb) + scol],                 \
                bb + 2048 + tid * 8);                                           \
        gload16(&BT[(size_t)(n0 + srow) * K + (kb) + scol],                     \
                bb + 4096 + tid * 8);                                           \
        gload16(&BT[(size_t)(n0 + 64 + srow) * K + (kb) + scol],                \
                bb + 6144 + tid * 8);                                           \
    } while (0)
    DSTAGE(0, 0);
    DSTAGE(1, 32);
#undef DSTAGE
    asm volatile("s_waitcnt vmcnt(0)" ::: "memory");
    __builtin_amdgcn_s_barrier();

    int bi = 0;
    for (int t = 0; t < 32; ++t) {
        __builtin_amdgcn_s_barrier();
        __builtin_amdgcn_sched_barrier(0);
        const ushort* bufA = SH + bi * 8192;
        const ushort* bufB = bufA + 4096;
        short8 a[4], b[4];
#pragma unroll
        for (int fm = 0; fm < 4; ++fm)
            a[fm] = *(const short8*)&bufA[(wr * 64 + fm * 16 + l15) * 32 + fcol];
#pragma unroll
        for (int fn = 0; fn < 4; ++fn)
            b[fn] = *(const short8*)&bufB[(wc * 64 + fn * 16 + l15) * 32 + fcol];
#pragma unroll
        for (int fm = 0; fm < 4; ++fm)
#pragma unroll
            for (int fn = 0; fn < 4; ++fn)
                acc[fm][fn] = MFMA(a[fm], b[fn], acc[fm][fn]);
        bi = (bi == 2) ? 0 : bi + 1;
    }
    f32x4 r = acc[0][0];
#pragma unroll
    for (int fm = 0; fm < 4; ++fm)
#pragma unroll
        for (int fn = 0; fn < 4; ++fn)
            if (fm | fn) r += acc[fm][fn];
    ((f32x4*)dump)[blockIdx.x * 256 + tid] = r;
}

// ---------------- flash attention, LDS-staged (T3 2-phase) ------------------
__global__ __launch_bounds__(256, 3) void k_attn(const ushort* __restrict__ Qh,
                                                 const ushort* __restrict__ Kh,
                                                 const ushort* __restrict__ Vt,
                                                 ushort* __restrict__ attnB) {
    __shared__ __align__(16) ushort Ks[2][64][64];   // 16 KB
    __shared__ __align__(16) ushort Vs[2][64][64];   // 16 KB
    __shared__ __align__(16) ushort P[4][16][72];    // 9 KB
    const int bh = blockIdx.x;
    const int g  = 15 - blockIdx.y;                  // q-tile, trip count g+1
    const int tid = threadIdx.x;
    const int wave = tid >> 6, lane = tid & 63;
    const int l15 = lane & 15, lhi = lane >> 4;
    const int b = bh >> 4, h = bh & 15;
    const ushort* Qp = Qh + (size_t)bh * S_LEN * 64;
    const ushort* Kp = Kh + (size_t)bh * S_LEN * 64;
    const ushort* Vp = Vt + (size_t)bh * 64 * S_LEN;
    const int qb = (g << 6) + (wave << 4);
    const int qrowb = qb + lhi * 4;

    const int U0 = tid, U1 = tid + 256;
    const int r0 = U0 >> 3, o0 = ((U0 & 7) ^ (r0 & 7)) << 3;   // ushort offset
    const int r1 = U1 >> 3, o1 = ((U1 & 7) ^ (r1 & 7)) << 3;
    ushort* KsF = &Ks[0][0][0];
    ushort* VsF = &Vs[0][0][0];

    short8 aQ0 = *(const short8*)&Qp[(size_t)(qb + l15) * 64 + lhi * 8];
    short8 aQ1 = *(const short8*)&Qp[(size_t)(qb + l15) * 64 + 32 + lhi * 8];

    short8 ones;
#pragma unroll
    for (int j = 0; j < 8; ++j) ones[j] = (short)0x3F80;   // bf16 1.0

    f32x4 O0{}, O1{}, O2{}, O3{}, ssum{};

    gload16(&Kp[(size_t)r0 * 64 + o0], KsF + U0 * 8);
    gload16(&Kp[(size_t)r1 * 64 + o1], KsF + U1 * 8);
    gload16(&Vp[(size_t)r0 * S_LEN + o0], VsF + U0 * 8);
    gload16(&Vp[(size_t)r1 * S_LEN + o1], VsF + U1 * 8);
    __syncthreads();

#define LDSK(s, kk) (*(const short8*)(KsF + (cur << 12) + ((((s) << 4) + l15) << 6) + \
                                      ((((kk) * 4 + lhi) ^ (l15 & 7)) << 3)))
#define LDSV(n, kk) (*(const short8*)(VsF + (cur << 12) + ((((n) << 4) + l15) << 6) + \
                                      ((((kk) * 4 + lhi) ^ (l15 & 7)) << 3)))

    int cur = 0;
    for (int kb = 0; kb <= g; ++kb) {
        const int k0 = kb << 6;
        if (kb < g) {
            const int kn = k0 + 64;
            const int bo = (cur ^ 1) << 12;
            gload16(&Kp[(size_t)(kn + r0) * 64 + o0], KsF + bo + U0 * 8);
            gload16(&Kp[(size_t)(kn + r1) * 64 + o1], KsF + bo + U1 * 8);
            gload16(&Vp[(size_t)r0 * S_LEN + kn + o0], VsF + bo + U0 * 8);
            gload16(&Vp[(size_t)r1 * S_LEN + kn + o1], VsF + bo + U1 * 8);
        }

        __builtin_amdgcn_s_setprio(1);
        f32x4 s0{}, s1{}, s2{}, s3{};
        s0 = MFMA(aQ0, LDSK(0, 0), s0); s0 = MFMA(aQ1, LDSK(0, 1), s0);
        s1 = MFMA(aQ0, LDSK(1, 0), s1); s1 = MFMA(aQ1, LDSK(1, 1), s1);
        s2 = MFMA(aQ0, LDSK(2, 0), s2); s2 = MFMA(aQ1, LDSK(2, 1), s2);
        s3 = MFMA(aQ0, LDSK(3, 0), s3); s3 = MFMA(aQ1, LDSK(3, 1), s3);
        __builtin_amdgcn_s_setprio(0);

        if (kb == g) {
#define EXPSTM(SV, SUB)                                                        \
    _Pragma("unroll") for (int i = 0; i < 4; ++i) {                            \
        float v = SV[i];                                                       \
        if (k0 + (SUB) * 16 + l15 > qrowb + i) v = -1e30f;                     \
        P[wave][lhi * 4 + i][(SUB) * 16 + l15] = f2bf(__expf(v - 8.f));        \
    }
            EXPSTM(s0, 0) EXPSTM(s1, 1) EXPSTM(s2, 2) EXPSTM(s3, 3)
#undef EXPSTM
        } else {
#define EXPST(SV, SUB)                                                         \
    _Pragma("unroll") for (int i = 0; i < 4; ++i) {                            \
        P[wave][lhi * 4 + i][(SUB) * 16 + l15] = f2bf(__expf(SV[i] - 8.f));    \
    }
            EXPST(s0, 0) EXPST(s1, 1) EXPST(s2, 2) EXPST(s3, 3)
#undef EXPST
        }

        short8 aP0 = *(const short8*)&P[wave][l15][lhi * 8];
        short8 aP1 = *(const short8*)&P[wave][l15][32 + lhi * 8];
        __builtin_amdgcn_s_setprio(1);
        ssum = MFMA(aP0, ones, ssum); ssum = MFMA(aP1, ones, ssum);
        O0 = MFMA(aP0, LDSV(0, 0), O0); O0 = MFMA(aP1, LDSV(0, 1), O0);
        O1 = MFMA(aP0, LDSV(1, 0), O1); O1 = MFMA(aP1, LDSV(1, 1), O1);
        O2 = MFMA(aP0, LDSV(2, 0), O2); O2 = MFMA(aP1, LDSV(2, 1), O2);
        O3 = MFMA(aP0, LDSV(3, 0), O3); O3 = MFMA(aP1, LDSV(3, 1), O3);
        __builtin_amdgcn_s_setprio(0);

        __syncthreads();
        cur ^= 1;
    }
#undef LDSK
#undef LDSV

    f32x4 inv;
#pragma unroll
    for (int i = 0; i < 4; ++i) inv[i] = 1.f / ssum[i];
#define WOUT(OV, N)                                                            \
    _Pragma("unroll") for (int i = 0; i < 4; ++i) {                            \
        int row = qb + lhi * 4 + i;                                            \
        attnB[((size_t)(b * S_LEN + row)) * DM + h * 64 + (N) * 16 + l15] =    \
            f2bf(OV[i] * inv[i]);                                              \
    }
    WOUT(O0, 0) WOUT(O1, 1) WOUT(O2, 2) WOUT(O3, 3)
#undef WOUT
}

// ---------------------------------------------------------------------------
extern "C" void kernel_launch(void* const* d_in, const int* in_sizes, int n_in,
                              void* d_out, int out_size, void* d_ws, size_t ws_size,
                              hipStream_t stream) {
    (void)in_sizes; (void)n_in; (void)out_size; (void)ws_size;
    const float* hs   = (const float*)d_in[0];
    const int*   pos  = (const int*)d_in[1];
    const float* Wqkv = (const float*)d_in[3];
    const float* Wout = (const float*)d_in[4];
    float* out = (float*)d_out;

    char* ws = (char*)d_ws;
    size_t off = 0;
    ushort* hsB   = (ushort*)(ws + off); off += (size_t)4096 * 1024 * 2;   // 8MB
    ushort* WqkvB = (ushort*)(ws + off); off += (size_t)3072 * 1024 * 2;   // 6MB
    ushort* WoutB = (ushort*)(ws + off); off += (size_t)1024 * 1024 * 2;   // 2MB
    ushort* Qh    = (ushort*)(ws + off); off += (size_t)NBH * 1024 * 64 * 2; // 8MB
    ushort* Kh    = (ushort*)(ws + off); off += (size_t)NBH * 1024 * 64 * 2; // 8MB
    ushort* Vt    = (ushort*)(ws + off); off += (size_t)NBH * 64 * 1024 * 2; // 8MB
    ushort* attnB = (ushort*)(ws + off); off += (size_t)4096 * 1024 * 2;   // 8MB
    float*  tab   = (float*)(ws + off);  off += (size_t)4096 * 32 * 2 * 4; // 1MB
    float*  dump  = (float*)(ws + off);  off += (size_t)768 * 256 * 16;    // 3MB

    k_build_tab<<<512, 256, 0, stream>>>(tab);
    k_cvt3<<<8192, 256, 0, stream>>>((const float4*)hs, (const float4*)Wqkv,
                                     (const float4*)Wout, (ushort4*)hsB,
                                     (ushort4*)WqkvB, (ushort4*)WoutB);

    // GEMM1 fused: qkv proj + RoPE + head split + V transpose
    k_gemm<1><<<768, 256, 0, stream>>>(hsB, WqkvB, nullptr, pos, tab,
                                       Qh, Kh, Vt, 4096, 3072, 1024, 24);

    k_attn<<<dim3(64, 16), 256, 0, stream>>>(Qh, Kh, Vt, attnB);

    // GEMM2: out projection, f32 output
    k_gemm<0><<<256, 256, 0, stream>>>(attnB, WoutB, out, nullptr, nullptr,
                                       nullptr, nullptr, nullptr, 4096, 1024, 1024, 8);

    // DIAGNOSTIC (scratch-only): K-loop cost without staging/vmcnt
    k_diag_nostage<<<768, 256, 0, stream>>>(hsB, WqkvB, dump);
}

// Round 11
// 97.674 us; speedup vs baseline: 1.3089x; 1.3089x over previous
//
#include <hip/hip_runtime.h>

typedef __attribute__((ext_vector_type(8))) short short8;
typedef __attribute__((ext_vector_type(4))) float f32x4;

#define MFMA(a, b, c) __builtin_amdgcn_mfma_f32_16x16x32_bf16((a), (b), (c), 0, 0, 0)

#define S_LEN 1024
#define DM 1024
#define NHEADS 16
#define HD 64
#define NBH 64          // B * NHEADS = 4 * 16
#define MAXPOS 4096

__device__ __forceinline__ ushort f2bf(float f) {
    unsigned u = __builtin_bit_cast(unsigned, f);
    u += 0x7fffu + ((u >> 16) & 1u);
    return (ushort)(u >> 16);
}
__device__ __forceinline__ float bf2f(ushort h) {
    return __builtin_bit_cast(float, (unsigned)h << 16);
}

// async global->LDS, 16B per lane. LDS dest must be base + lane*16 linear.
__device__ __forceinline__ void gload16(const ushort* g, ushort* l) {
    __builtin_amdgcn_global_load_lds(
        (const __attribute__((address_space(1))) unsigned int*)g,
        (__attribute__((address_space(3))) unsigned int*)l, 16, 0, 0);
}

// ---------------- RoPE table: tab[p][i] = {cos, sin}, p<4096, i<32 ----------
__global__ __launch_bounds__(256) void k_build_tab(float* __restrict__ tab) {
    int id = blockIdx.x * 256 + threadIdx.x;      // 4096*32 entries
    int p = id >> 5, i = id & 31;
    float inv = powf(10000.f, -(float)(2 * i) / 64.f);
    float t = (float)p * inv;
    float s, c;
    sincosf(t, &s, &c);
    tab[2 * id] = c;
    tab[2 * id + 1] = s;
}

// ---------------- fp32 -> bf16 conversion, all three tensors, one launch ----
__global__ __launch_bounds__(256) void k_cvt3(const float4* __restrict__ hs,
                                              const float4* __restrict__ wqkv,
                                              const float4* __restrict__ wout,
                                              ushort4* __restrict__ hsB,
                                              ushort4* __restrict__ wqkvB,
                                              ushort4* __restrict__ woutB) {
    int id = blockIdx.x * 256 + threadIdx.x;
    const float4* src;
    ushort4* dst;
    int off;
    if (id < 1048576)      { src = hs;   dst = hsB;   off = id; }
    else if (id < 1835008) { src = wqkv; dst = wqkvB; off = id - 1048576; }
    else                   { src = wout; dst = woutB; off = id - 1835008; }
    float4 v = src[off];
    ushort4 o;
    o.x = f2bf(v.x); o.y = f2bf(v.y); o.z = f2bf(v.z); o.w = f2bf(v.w);
    dst[off] = o;
}

// ---------------- GEMM1: 256x256 tile, 8 waves, counted-vmcnt ring ----------
// qkv = hs @ Wqkv^T fused with RoPE/head-split/V-transpose epilogue.
// Ring: BK=32, 4 LDS bufs (128 KB), stage 3 K-tiles ahead, vmcnt(8) at tile
// top (8 = 2 tiles x 4 loads in flight; tail 8->4->0), raw s_barrier.
// Wave grid 2x4, wave tile 128x64 (acc[8][4]).
// T2 chunk-XOR swizzle identical to the 128^2 ring (pre-swizzled DMA source).
__global__ __launch_bounds__(512, 2) void k_gemm256(
    const ushort* __restrict__ A, const ushort* __restrict__ BT,
    const int* __restrict__ pos, const float* __restrict__ tab,
    ushort* __restrict__ Qh, ushort* __restrict__ Kh, ushort* __restrict__ Vt) {
    __shared__ __align__(16) ushort SH[4 * 16384];   // 4 bufs x (A 256x32 | B 256x32) = 128 KB
    const int K = 1024;
    const int tid = threadIdx.x;                 // 0..511
    const int lane = tid & 63, wave = tid >> 6;  // 8 waves
    const int wr = wave >> 2, wc = wave & 3;     // 2 x 4
    const int l15 = lane & 15, lhi = lane >> 4;
    const int bx = blockIdx.x % 12, by = blockIdx.x / 12;
    const int m0 = by << 8, n0 = bx << 8;
    // read-side swizzled chunk offset (4 chunks of 8 ushorts per 32-elem row)
    const int fcol = ((lhi ^ ((l15 & 3) ^ ((l15 >> 2) & 3)))) << 3;

    f32x4 acc[8][4];
#pragma unroll
    for (int i = 0; i < 8; ++i)
#pragma unroll
        for (int j = 0; j < 4; ++j) acc[i][j] = 0;

    // staging: 2048 chunks (A 1024 | B 1024), 4 per thread; unit u covers
    // row (u&1023)>>2, chunk u&3, dest linear u*8; source chunk pre-swizzled.
#define STAGE(bs, kb)                                                           \
    do {                                                                        \
        ushort* bb = SH + (bs) * 16384;                                         \
        _Pragma("unroll") for (int k = 0; k < 4; ++k) {                         \
            const int u = tid + k * 512;                                        \
            const int r = (u & 1023) >> 2;                                      \
            const int sc = ((u & 3) ^ (r & 3) ^ ((r >> 2) & 3)) << 3;           \
            const ushort* src = (k < 2)                                         \
                ? &A[(size_t)(m0 + r) * K + (kb) + sc]                          \
                : &BT[(size_t)(n0 + r) * K + (kb) + sc];                        \
            gload16(src, bb + u * 8);                                           \
        }                                                                       \
    } while (0)

    const int nk = K >> 5;              // 32 tiles, BK = 32
    STAGE(0, 0);
    STAGE(1, 32);
    STAGE(2, 64);
    int bi = 0;
    for (int t = 0; t < nk; ++t) {
        if (t + 2 < nk) {
            asm volatile("s_waitcnt vmcnt(8)" ::: "memory");
        } else if (t + 1 < nk) {
            asm volatile("s_waitcnt vmcnt(4)" ::: "memory");
        } else {
            asm volatile("s_waitcnt vmcnt(0)" ::: "memory");
        }
        __builtin_amdgcn_s_barrier();
        __builtin_amdgcn_sched_barrier(0);   // nothing crosses the publish point
        if (t + 3 < nk) STAGE((bi + 3) & 3, (t + 3) << 5);
        const ushort* buf = SH + bi * 16384;
        short8 afr[8], bfr[4];
#pragma unroll
        for (int nf = 0; nf < 4; ++nf)
            bfr[nf] = *(const short8*)&buf[8192 + (wc * 64 + nf * 16 + l15) * 32 + fcol];
#pragma unroll
        for (int mf = 0; mf < 8; ++mf)
            afr[mf] = *(const short8*)&buf[(wr * 128 + mf * 16 + l15) * 32 + fcol];
#pragma unroll
        for (int mf = 0; mf < 8; ++mf)
#pragma unroll
            for (int nf = 0; nf < 4; ++nf)
                acc[mf][nf] = MFMA(afr[mf], bfr[nf], acc[mf][nf]);
        bi = (bi + 1) & 3;
    }
#undef STAGE
    __syncthreads();                    // main-loop LDS dead before reuse

    const int sec = n0 >> 10;                       // 0=q, 1=k, 2=v (tiles align)
    if (sec < 2) {
        ushort* dstb = sec == 0 ? Qh : Kh;
        const float qs = sec == 0 ? 0.125f : 1.0f;
#pragma unroll
        for (int mf = 0; mf < 8; ++mf)
#pragma unroll
            for (int i = 0; i < 4; ++i) {
                const int row = m0 + wr * 128 + mf * 16 + lhi * 4 + i;
                const int b = row >> 10, s = row & 1023;
                int p = pos[s];
                p = p < 0 ? 0 : (p > MAXPOS - 1 ? MAXPOS - 1 : p);
#pragma unroll
                for (int nf = 0; nf < 4; ++nf) {
                    const int col = n0 + wc * 64 + nf * 16 + l15;
                    const int cw = col & 1023;
                    const int h = cw >> 6, d = cw & 63;
                    const float c  = tab[((size_t)p * 32 + (d >> 1)) * 2];
                    const float sn = tab[((size_t)p * 32 + (d >> 1)) * 2 + 1];
                    const float v = acc[mf][nf][i];
                    const float pr = __shfl_xor(v, 1);
                    const float o = (d & 1) ? (v * c + pr * sn) : (v * c - pr * sn);
                    dstb[((size_t)((b * 16 + h) * 1024 + s)) * 64 + d] = f2bf(o * qs);
                }
            }
    } else {
        // V: transpose via LDS bounce, two 128-row halves.
        // Tile is 256 columns wide -> T[128][264] (264 = 256 + 8 pad).
        // (R10 bug: [132] second dim aliased T[r][c>=132] into row r+1.)
        ushort (*T)[264] = (ushort(*)[264]) & SH[0];   // 67.6 KB of the 128 KB SH
        const int bb = m0 >> 10;
        const int dd = tid & 255, sg = tid >> 8;     // dd: 4 heads x 64 dims
        const int hv = ((n0 & 1023) >> 6) + (dd >> 6);
        const int d = dd & 63;
#pragma unroll
        for (int h = 0; h < 2; ++h) {
            if (wr == h) {
#pragma unroll
                for (int mf = 0; mf < 8; ++mf)
#pragma unroll
                    for (int nf = 0; nf < 4; ++nf)
#pragma unroll
                        for (int i = 0; i < 4; ++i)
                            T[mf * 16 + lhi * 4 + i][wc * 64 + nf * 16 + l15] =
                                f2bf(acc[mf][nf][i]);
            }
            __syncthreads();
            const int s0 = (m0 & 1023) + h * 128;
            ushort* dst = Vt + ((size_t)(bb * 16 + hv) * 64 + d) * S_LEN + s0;
#pragma unroll
            for (int j = 0; j < 8; ++j) {
                const int ch = sg * 8 + j;           // 16 chunks of 8 seq
                __align__(16) ushort tmp[8];
#pragma unroll
                for (int e = 0; e < 8; ++e) tmp[e] = T[ch * 8 + e][dd];
                *(uint4*)&dst[ch * 8] = *(uint4*)tmp;
            }
            __syncthreads();
        }
    }
}

// ---------------- bf16 GEMM (128^2 ring) — used for the out-projection ------
template <int MODE>
__global__ __launch_bounds__(256, 3) void k_gemm(
    const ushort* __restrict__ A, const ushort* __restrict__ BT,
    float* __restrict__ Cf,
    const int* __restrict__ pos, const float* __restrict__ tab,
    ushort* __restrict__ Qh, ushort* __restrict__ Kh, ushort* __restrict__ Vt,
    int M, int N, int K, int nbx) {
    __shared__ __align__(16) ushort SH[3 * 8192];   // 48 KB
    const int tid = threadIdx.x;
    const int lane = tid & 63, wave = tid >> 6;
    const int wr = wave >> 1, wc = wave & 1;
    const int l15 = lane & 15, lhi = lane >> 4;
    const int nby = gridDim.x / nbx;
    const int xcd = blockIdx.x & 7, idx = blockIdx.x >> 3;
    const int Creg = nbx >> 1, Rreg = nby >> 2;
    const int by = (xcd >> 1) * Rreg + idx / Creg;
    const int bx = (xcd & 1) * Creg + idx % Creg;
    const int m0 = by << 7, n0 = bx << 7;

    const int srow = tid >> 2;                                        // 0..63
    const int scol = (((tid >> 2) & 3) ^ ((tid >> 4) & 3) ^ (tid & 3)) << 3;
    const int fcol = ((lhi ^ ((l15 & 3) ^ ((l15 >> 2) & 3)))) << 3;

    f32x4 acc[4][4];
#pragma unroll
    for (int i = 0; i < 4; ++i)
#pragma unroll
        for (int j = 0; j < 4; ++j) acc[i][j] = 0;

#define STAGE(bs, kb)                                                           \
    do {                                                                        \
        ushort* bb = SH + (bs) * 8192;                                          \
        gload16(&A[(size_t)(m0 + srow) * K + (kb) + scol], bb + tid * 8);       \
        gload16(&A[(size_t)(m0 + 64 + srow) * K + (kb) + scol],                 \
                bb + 2048 + tid * 8);                                           \
        gload16(&BT[(size_t)(n0 + srow) * K + (kb) + scol],                     \
                bb + 4096 + tid * 8);                                           \
        gload16(&BT[(size_t)(n0 + 64 + srow) * K + (kb) + scol],                \
                bb + 6144 + tid * 8);                                           \
    } while (0)

    const int nk = K >> 5;              // BK = 32
    STAGE(0, 0);
    STAGE(1, 32);
    int bi = 0;
    for (int t = 0; t < nk; ++t) {
        if (t + 1 < nk) {
            asm volatile("s_waitcnt vmcnt(4)" ::: "memory");
        } else {
            asm volatile("s_waitcnt vmcnt(0)" ::: "memory");
        }
        __builtin_amdgcn_s_barrier();
        __builtin_amdgcn_sched_barrier(0);
        if (t + 2 < nk) {
            int bs = bi + 2;
            if (bs >= 3) bs -= 3;
            STAGE(bs, (t + 2) << 5);
        }
        const ushort* bufA = SH + bi * 8192;
        const ushort* bufB = bufA + 4096;
        short8 a[4], b[4];
#pragma unroll
        for (int fm = 0; fm < 4; ++fm)
            a[fm] = *(const short8*)&bufA[(wr * 64 + fm * 16 + l15) * 32 + fcol];
#pragma unroll
        for (int fn = 0; fn < 4; ++fn)
            b[fn] = *(const short8*)&bufB[(wc * 64 + fn * 16 + l15) * 32 + fcol];
#pragma unroll
        for (int fm = 0; fm < 4; ++fm)
#pragma unroll
            for (int fn = 0; fn < 4; ++fn)
                acc[fm][fn] = MFMA(a[fm], b[fn], acc[fm][fn]);
        bi = (bi == 2) ? 0 : bi + 1;
    }
#undef STAGE

    if (MODE == 0) {
#pragma unroll
        for (int fm = 0; fm < 4; ++fm)
#pragma unroll
            for (int fn = 0; fn < 4; ++fn)
#pragma unroll
                for (int i = 0; i < 4; ++i) {
                    int row = m0 + wr * 64 + fm * 16 + lhi * 4 + i;
                    int col = n0 + wc * 64 + fn * 16 + l15;
                    Cf[(size_t)row * N + col] = acc[fm][fn][i];
                }
    }
}

// ---------------- flash attention, LDS-staged (T3 2-phase) ------------------
__global__ __launch_bounds__(256, 3) void k_attn(const ushort* __restrict__ Qh,
                                                 const ushort* __restrict__ Kh,
                                                 const ushort* __restrict__ Vt,
                                                 ushort* __restrict__ attnB) {
    __shared__ __align__(16) ushort Ks[2][64][64];   // 16 KB
    __shared__ __align__(16) ushort Vs[2][64][64];   // 16 KB
    __shared__ __align__(16) ushort P[4][16][72];    // 9 KB
    const int bh = blockIdx.x;
    const int g  = 15 - blockIdx.y;                  // q-tile, trip count g+1
    const int tid = threadIdx.x;
    const int wave = tid >> 6, lane = tid & 63;
    const int l15 = lane & 15, lhi = lane >> 4;
    const int b = bh >> 4, h = bh & 15;
    const ushort* Qp = Qh + (size_t)bh * S_LEN * 64;
    const ushort* Kp = Kh + (size_t)bh * S_LEN * 64;
    const ushort* Vp = Vt + (size_t)bh * 64 * S_LEN;
    const int qb = (g << 6) + (wave << 4);
    const int qrowb = qb + lhi * 4;

    const int U0 = tid, U1 = tid + 256;
    const int r0 = U0 >> 3, o0 = ((U0 & 7) ^ (r0 & 7)) << 3;   // ushort offset
    const int r1 = U1 >> 3, o1 = ((U1 & 7) ^ (r1 & 7)) << 3;
    ushort* KsF = &Ks[0][0][0];
    ushort* VsF = &Vs[0][0][0];

    short8 aQ0 = *(const short8*)&Qp[(size_t)(qb + l15) * 64 + lhi * 8];
    short8 aQ1 = *(const short8*)&Qp[(size_t)(qb + l15) * 64 + 32 + lhi * 8];

    short8 ones;
#pragma unroll
    for (int j = 0; j < 8; ++j) ones[j] = (short)0x3F80;   // bf16 1.0

    f32x4 O0{}, O1{}, O2{}, O3{}, ssum{};

    gload16(&Kp[(size_t)r0 * 64 + o0], KsF + U0 * 8);
    gload16(&Kp[(size_t)r1 * 64 + o1], KsF + U1 * 8);
    gload16(&Vp[(size_t)r0 * S_LEN + o0], VsF + U0 * 8);
    gload16(&Vp[(size_t)r1 * S_LEN + o1], VsF + U1 * 8);
    __syncthreads();

#define LDSK(s, kk) (*(const short8*)(KsF + (cur << 12) + ((((s) << 4) + l15) << 6) + \
                                      ((((kk) * 4 + lhi) ^ (l15 & 7)) << 3)))
#define LDSV(n, kk) (*(const short8*)(VsF + (cur << 12) + ((((n) << 4) + l15) << 6) + \
                                      ((((kk) * 4 + lhi) ^ (l15 & 7)) << 3)))

    int cur = 0;
    for (int kb = 0; kb <= g; ++kb) {
        const int k0 = kb << 6;
        if (kb < g) {
            const int kn = k0 + 64;
            const int bo = (cur ^ 1) << 12;
            gload16(&Kp[(size_t)(kn + r0) * 64 + o0], KsF + bo + U0 * 8);
            gload16(&Kp[(size_t)(kn + r1) * 64 + o1], KsF + bo + U1 * 8);
            gload16(&Vp[(size_t)r0 * S_LEN + kn + o0], VsF + bo + U0 * 8);
            gload16(&Vp[(size_t)r1 * S_LEN + kn + o1], VsF + bo + U1 * 8);
        }

        __builtin_amdgcn_s_setprio(1);
        f32x4 s0{}, s1{}, s2{}, s3{};
        s0 = MFMA(aQ0, LDSK(0, 0), s0); s0 = MFMA(aQ1, LDSK(0, 1), s0);
        s1 = MFMA(aQ0, LDSK(1, 0), s1); s1 = MFMA(aQ1, LDSK(1, 1), s1);
        s2 = MFMA(aQ0, LDSK(2, 0), s2); s2 = MFMA(aQ1, LDSK(2, 1), s2);
        s3 = MFMA(aQ0, LDSK(3, 0), s3); s3 = MFMA(aQ1, LDSK(3, 1), s3);
        __builtin_amdgcn_s_setprio(0);

        if (kb == g) {
#define EXPSTM(SV, SUB)                                                        \
    _Pragma("unroll") for (int i = 0; i < 4; ++i) {                            \
        float v = SV[i];                                                       \
        if (k0 + (SUB) * 16 + l15 > qrowb + i) v = -1e30f;                     \
        P[wave][lhi * 4 + i][(SUB) * 16 + l15] = f2bf(__expf(v - 8.f));        \
    }
            EXPSTM(s0, 0) EXPSTM(s1, 1) EXPSTM(s2, 2) EXPSTM(s3, 3)
#undef EXPSTM
        } else {
#define EXPST(SV, SUB)                                                         \
    _Pragma("unroll") for (int i = 0; i < 4; ++i) {                            \
        P[wave][lhi * 4 + i][(SUB) * 16 + l15] = f2bf(__expf(SV[i] - 8.f));    \
    }
            EXPST(s0, 0) EXPST(s1, 1) EXPST(s2, 2) EXPST(s3, 3)
#undef EXPST
        }

        short8 aP0 = *(const short8*)&P[wave][l15][lhi * 8];
        short8 aP1 = *(const short8*)&P[wave][l15][32 + lhi * 8];
        __builtin_amdgcn_s_setprio(1);
        ssum = MFMA(aP0, ones, ssum); ssum = MFMA(aP1, ones, ssum);
        O0 = MFMA(aP0, LDSV(0, 0), O0); O0 = MFMA(aP1, LDSV(0, 1), O0);
        O1 = MFMA(aP0, LDSV(1, 0), O1); O1 = MFMA(aP1, LDSV(1, 1), O1);
        O2 = MFMA(aP0, LDSV(2, 0), O2); O2 = MFMA(aP1, LDSV(2, 1), O2);
        O3 = MFMA(aP0, LDSV(3, 0), O3); O3 = MFMA(aP1, LDSV(3, 1), O3);
        __builtin_amdgcn_s_setprio(0);

        __syncthreads();
        cur ^= 1;
    }
#undef LDSK
#undef LDSV

    f32x4 inv;
#pragma unroll
    for (int i = 0; i < 4; ++i) inv[i] = 1.f / ssum[i];
#define WOUT(OV, N)                                                            \
    _Pragma("unroll") for (int i = 0; i < 4; ++i) {                            \
        int row = qb + lhi * 4 + i;                                            \
        attnB[((size_t)(b * S_LEN + row)) * DM + h * 64 + (N) * 16 + l15] =    \
            f2bf(OV[i] * inv[i]);                                              \
    }
    WOUT(O0, 0) WOUT(O1, 1) WOUT(O2, 2) WOUT(O3, 3)
#undef WOUT
}

// ---------------------------------------------------------------------------
extern "C" void kernel_launch(void* const* d_in, const int* in_sizes, int n_in,
                              void* d_out, int out_size, void* d_ws, size_t ws_size,
                              hipStream_t stream) {
    (void)in_sizes; (void)n_in; (void)out_size; (void)ws_size;
    const float* hs   = (const float*)d_in[0];
    const int*   pos  = (const int*)d_in[1];
    const float* Wqkv = (const float*)d_in[3];
    const float* Wout = (const float*)d_in[4];
    float* out = (float*)d_out;

    char* ws = (char*)d_ws;
    size_t off = 0;
    ushort* hsB   = (ushort*)(ws + off); off += (size_t)4096 * 1024 * 2;   // 8MB
    ushort* WqkvB = (ushort*)(ws + off); off += (size_t)3072 * 1024 * 2;   // 6MB
    ushort* WoutB = (ushort*)(ws + off); off += (size_t)1024 * 1024 * 2;   // 2MB
    ushort* Qh    = (ushort*)(ws + off); off += (size_t)NBH * 1024 * 64 * 2; // 8MB
    ushort* Kh    = (ushort*)(ws + off); off += (size_t)NBH * 1024 * 64 * 2; // 8MB
    ushort* Vt    = (ushort*)(ws + off); off += (size_t)NBH * 64 * 1024 * 2; // 8MB
    ushort* attnB = (ushort*)(ws + off); off += (size_t)4096 * 1024 * 2;   // 8MB
    float*  tab   = (float*)(ws + off);  off += (size_t)4096 * 32 * 2 * 4; // 1MB

    k_build_tab<<<512, 256, 0, stream>>>(tab);
    k_cvt3<<<8192, 256, 0, stream>>>((const float4*)hs, (const float4*)Wqkv,
                                     (const float4*)Wout, (ushort4*)hsB,
                                     (ushort4*)WqkvB, (ushort4*)WoutB);

    // GEMM1 fused: qkv proj + RoPE + head split + V transpose (256^2, 8-wave)
    k_gemm256<<<192, 512, 0, stream>>>(hsB, WqkvB, pos, tab, Qh, Kh, Vt);

    k_attn<<<dim3(64, 16), 256, 0, stream>>>(Qh, Kh, Vt, attnB);

    // GEMM2: out projection, f32 output (128^2 ring)
    k_gemm<0><<<256, 256, 0, stream>>>(attnB, WoutB, out, nullptr, nullptr,
                                       nullptr, nullptr, nullptr, 4096, 1024, 1024, 8);
}

// Round 12
// 93.141 us; speedup vs baseline: 1.3726x; 1.0487x over previous
//
#include <hip/hip_runtime.h>

typedef __attribute__((ext_vector_type(8))) short short8;
typedef __attribute__((ext_vector_type(4))) float f32x4;

#define MFMA(a, b, c) __builtin_amdgcn_mfma_f32_16x16x32_bf16((a), (b), (c), 0, 0, 0)

#define S_LEN 1024
#define DM 1024
#define NHEADS 16
#define HD 64
#define NBH 64          // B * NHEADS = 4 * 16
#define MAXPOS 4096

__device__ __forceinline__ ushort f2bf(float f) {
    unsigned u = __builtin_bit_cast(unsigned, f);
    u += 0x7fffu + ((u >> 16) & 1u);
    return (ushort)(u >> 16);
}
__device__ __forceinline__ float bf2f(ushort h) {
    return __builtin_bit_cast(float, (unsigned)h << 16);
}

// async global->LDS, 16B per lane. LDS dest must be base + lane*16 linear.
__device__ __forceinline__ void gload16(const ushort* g, ushort* l) {
    __builtin_amdgcn_global_load_lds(
        (const __attribute__((address_space(1))) unsigned int*)g,
        (__attribute__((address_space(3))) unsigned int*)l, 16, 0, 0);
}

// ------- fp32 -> bf16 conversion (3 tensors) + RoPE table, one launch -------
// ids [0, 2097152): conversions; ids [2097152, 2228224): tab. Block-uniform.
__global__ __launch_bounds__(256) void k_cvt3(const float4* __restrict__ hs,
                                              const float4* __restrict__ wqkv,
                                              const float4* __restrict__ wout,
                                              ushort4* __restrict__ hsB,
                                              ushort4* __restrict__ wqkvB,
                                              ushort4* __restrict__ woutB,
                                              float* __restrict__ tab) {
    int id = blockIdx.x * 256 + threadIdx.x;
    if (id < 2097152) {
        const float4* src;
        ushort4* dst;
        int off;
        if (id < 1048576)      { src = hs;   dst = hsB;   off = id; }
        else if (id < 1835008) { src = wqkv; dst = wqkvB; off = id - 1048576; }
        else                   { src = wout; dst = woutB; off = id - 1835008; }
        float4 v = src[off];
        ushort4 o;
        o.x = f2bf(v.x); o.y = f2bf(v.y); o.z = f2bf(v.z); o.w = f2bf(v.w);
        dst[off] = o;
    } else {
        int t = id - 2097152;             // 0..131071 = 4096 pos x 32 freq
        int p = t >> 5, i = t & 31;
        float inv = powf(10000.f, -(float)(2 * i) / 64.f);
        float th = (float)p * inv;
        float s, c;
        sincosf(th, &s, &c);
        tab[2 * t] = c;
        tab[2 * t + 1] = s;
    }
}

// ---------------- bf16 GEMM, C = A @ B^T, 128x128 tile ----------------------
// Counted-vmcnt ring (T3/T4): BK=32, 3 LDS bufs, 2 K-tiles ahead, vmcnt(4),
// raw s_barrier; compiler-scheduled ds_read/MFMA interleave. T2 XOR swizzle.
// MODE 0: f32 C. MODE 1: fused RoPE/head-split/V-transpose epilogue.
template <int MODE>
__global__ __launch_bounds__(256, 3) void k_gemm(
    const ushort* __restrict__ A, const ushort* __restrict__ BT,
    float* __restrict__ Cf,
    const int* __restrict__ pos, const float* __restrict__ tab,
    ushort* __restrict__ Qh, ushort* __restrict__ Kh, ushort* __restrict__ Vt,
    int M, int N, int K, int nbx) {
    __shared__ __align__(16) ushort SH[3 * 8192];   // 48 KB
    const int tid = threadIdx.x;
    const int lane = tid & 63, wave = tid >> 6;
    const int wr = wave >> 1, wc = wave & 1;
    const int l15 = lane & 15, lhi = lane >> 4;
    const int nby = gridDim.x / nbx;
    const int xcd = blockIdx.x & 7, idx = blockIdx.x >> 3;
    const int Creg = nbx >> 1, Rreg = nby >> 2;
    const int by = (xcd >> 1) * Rreg + idx / Creg;
    const int bx = (xcd & 1) * Creg + idx % Creg;
    const int m0 = by << 7, n0 = bx << 7;

    const int srow = tid >> 2;                                        // 0..63
    const int scol = (((tid >> 2) & 3) ^ ((tid >> 4) & 3) ^ (tid & 3)) << 3;
    const int fcol = ((lhi ^ ((l15 & 3) ^ ((l15 >> 2) & 3)))) << 3;

    f32x4 acc[4][4];
#pragma unroll
    for (int i = 0; i < 4; ++i)
#pragma unroll
        for (int j = 0; j < 4; ++j) acc[i][j] = 0;

#define STAGE(bs, kb)                                                           \
    do {                                                                        \
        ushort* bb = SH + (bs) * 8192;                                          \
        gload16(&A[(size_t)(m0 + srow) * K + (kb) + scol], bb + tid * 8);       \
        gload16(&A[(size_t)(m0 + 64 + srow) * K + (kb) + scol],                 \
                bb + 2048 + tid * 8);                                           \
        gload16(&BT[(size_t)(n0 + srow) * K + (kb) + scol],                     \
                bb + 4096 + tid * 8);                                           \
        gload16(&BT[(size_t)(n0 + 64 + srow) * K + (kb) + scol],                \
                bb + 6144 + tid * 8);                                           \
    } while (0)

    const int nk = K >> 5;              // BK = 32
    STAGE(0, 0);
    STAGE(1, 32);
    int bi = 0;
    for (int t = 0; t < nk; ++t) {
        if (t + 1 < nk) {
            asm volatile("s_waitcnt vmcnt(4)" ::: "memory");
        } else {
            asm volatile("s_waitcnt vmcnt(0)" ::: "memory");
        }
        __builtin_amdgcn_s_barrier();
        __builtin_amdgcn_sched_barrier(0);   // pin: nothing crosses the publish point
        if (t + 2 < nk) {
            int bs = bi + 2;
            if (bs >= 3) bs -= 3;
            STAGE(bs, (t + 2) << 5);
        }
        const ushort* bufA = SH + bi * 8192;
        const ushort* bufB = bufA + 4096;
        short8 a[4], b[4];
#pragma unroll
        for (int fm = 0; fm < 4; ++fm)
            a[fm] = *(const short8*)&bufA[(wr * 64 + fm * 16 + l15) * 32 + fcol];
#pragma unroll
        for (int fn = 0; fn < 4; ++fn)
            b[fn] = *(const short8*)&bufB[(wc * 64 + fn * 16 + l15) * 32 + fcol];
#pragma unroll
        for (int fm = 0; fm < 4; ++fm)
#pragma unroll
            for (int fn = 0; fn < 4; ++fn)
                acc[fm][fn] = MFMA(a[fm], b[fn], acc[fm][fn]);
        bi = (bi == 2) ? 0 : bi + 1;
    }
#undef STAGE
    __syncthreads();                    // LDS reuse (V-transpose bounce) safety

    if (MODE == 0) {
#pragma unroll
        for (int fm = 0; fm < 4; ++fm)
#pragma unroll
            for (int fn = 0; fn < 4; ++fn)
#pragma unroll
                for (int i = 0; i < 4; ++i) {
                    int row = m0 + wr * 64 + fm * 16 + lhi * 4 + i;
                    int col = n0 + wc * 64 + fn * 16 + l15;
                    Cf[(size_t)row * N + col] = acc[fm][fn][i];
                }
    } else {
        const int sec = n0 >> 10;                       // 0=q, 1=k, 2=v
        if (sec < 2) {
            ushort* dstb = sec == 0 ? Qh : Kh;
            const float qs = sec == 0 ? 0.125f : 1.0f;
#pragma unroll
            for (int fm = 0; fm < 4; ++fm)
#pragma unroll
                for (int i = 0; i < 4; ++i) {
                    const int row = m0 + wr * 64 + fm * 16 + lhi * 4 + i;
                    const int b = row >> 10, s = row & 1023;
                    int p = pos[s];
                    p = p < 0 ? 0 : (p > MAXPOS - 1 ? MAXPOS - 1 : p);
#pragma unroll
                    for (int fn = 0; fn < 4; ++fn) {
                        const int col = n0 + wc * 64 + fn * 16 + l15;
                        const int cw = col & 1023;
                        const int h = cw >> 6, d = cw & 63;
                        const float c  = tab[((size_t)p * 32 + (d >> 1)) * 2];
                        const float sn = tab[((size_t)p * 32 + (d >> 1)) * 2 + 1];
                        const float v = acc[fm][fn][i];
                        const float pr = __shfl_xor(v, 1);
                        const float o = (d & 1) ? (v * c + pr * sn) : (v * c - pr * sn);
                        dstb[((size_t)((b * 16 + h) * 1024 + s)) * 64 + d] = f2bf(o * qs);
                    }
                }
        } else {
            // V: transpose via LDS bounce (reuse staging buffer), [128][132] pad
            ushort (*T)[132] = (ushort(*)[132]) & SH[0];
#pragma unroll
            for (int fm = 0; fm < 4; ++fm)
#pragma unroll
                for (int fn = 0; fn < 4; ++fn)
#pragma unroll
                    for (int i = 0; i < 4; ++i)
                        T[wr * 64 + fm * 16 + lhi * 4 + i][wc * 64 + fn * 16 + l15] =
                            f2bf(acc[fm][fn][i]);
            __syncthreads();
            const int b = m0 >> 10, s0 = m0 & 1023;
            const int dd = tid & 127, scg = tid >> 7;   // dd: 2 heads x 64 dims
            const int hv = ((n0 & 1023) >> 6) + (dd >> 6);
            const int d = dd & 63;
            ushort* dst = Vt + ((size_t)(b * 16 + hv) * 64 + d) * S_LEN + s0;
#pragma unroll
            for (int j = 0; j < 8; ++j) {
                const int ch = scg * 8 + j;             // 16 chunks of 8 seq
                __align__(16) ushort tmp[8];
#pragma unroll
                for (int e = 0; e < 8; ++e) tmp[e] = T[ch * 8 + e][dd];
                *(uint4*)&dst[ch * 8] = *(uint4*)tmp;
            }
        }
    }
}

// ---------------- flash attention, dual q-tile per block --------------------
// Block (bh, g): q-tiles A = g (light) and B = 15-g (heavy) share one staged
// KV stream kb = 0..15-g. Tile A participates only for kb <= g. Uniform 17
// MFMA-tiles/block; KV staging volume -27% vs one-tile blocks; grid 512.
// Inner machinery (swizzle, fixed-offset exp, P round-trip, masking) is the
// proven single-tile code instantiated twice.
__global__ __launch_bounds__(256, 3) void k_attn(const ushort* __restrict__ Qh,
                                                 const ushort* __restrict__ Kh,
                                                 const ushort* __restrict__ Vt,
                                                 ushort* __restrict__ attnB) {
    __shared__ __align__(16) ushort Ks[2][64][64];   // 16 KB
    __shared__ __align__(16) ushort Vs[2][64][64];   // 16 KB
    __shared__ __align__(16) ushort P[4][16][72];    // 9 KB
    const int bh = blockIdx.x;
    const int g  = blockIdx.y;                       // 0..7
    const int gA = g, gB = 15 - g;
    const int nkb = gB + 1;                          // 9..16 loop iters
    const int tid = threadIdx.x;
    const int wave = tid >> 6, lane = tid & 63;
    const int l15 = lane & 15, lhi = lane >> 4;
    const int b = bh >> 4, h = bh & 15;
    const ushort* Qp = Qh + (size_t)bh * S_LEN * 64;
    const ushort* Kp = Kh + (size_t)bh * S_LEN * 64;
    const ushort* Vp = Vt + (size_t)bh * 64 * S_LEN;
    const int qbA = (gA << 6) + (wave << 4);
    const int qbB = (gB << 6) + (wave << 4);
    const int qrowbA = qbA + lhi * 4;
    const int qrowbB = qbB + lhi * 4;

    const int U0 = tid, U1 = tid + 256;
    const int r0 = U0 >> 3, o0 = ((U0 & 7) ^ (r0 & 7)) << 3;   // ushort offset
    const int r1 = U1 >> 3, o1 = ((U1 & 7) ^ (r1 & 7)) << 3;
    ushort* KsF = &Ks[0][0][0];
    ushort* VsF = &Vs[0][0][0];

    short8 aQA0 = *(const short8*)&Qp[(size_t)(qbA + l15) * 64 + lhi * 8];
    short8 aQA1 = *(const short8*)&Qp[(size_t)(qbA + l15) * 64 + 32 + lhi * 8];
    short8 aQB0 = *(const short8*)&Qp[(size_t)(qbB + l15) * 64 + lhi * 8];
    short8 aQB1 = *(const short8*)&Qp[(size_t)(qbB + l15) * 64 + 32 + lhi * 8];

    short8 ones;
#pragma unroll
    for (int j = 0; j < 8; ++j) ones[j] = (short)0x3F80;   // bf16 1.0

    f32x4 OA0{}, OA1{}, OA2{}, OA3{}, ssumA{};
    f32x4 OB0{}, OB1{}, OB2{}, OB3{}, ssumB{};

    gload16(&Kp[(size_t)r0 * 64 + o0], KsF + U0 * 8);
    gload16(&Kp[(size_t)r1 * 64 + o1], KsF + U1 * 8);
    gload16(&Vp[(size_t)r0 * S_LEN + o0], VsF + U0 * 8);
    gload16(&Vp[(size_t)r1 * S_LEN + o1], VsF + U1 * 8);
    __syncthreads();

#define LDSK(s, kk) (*(const short8*)(KsF + (cur << 12) + ((((s) << 4) + l15) << 6) + \
                                      ((((kk) * 4 + lhi) ^ (l15 & 7)) << 3)))
#define LDSV(n, kk) (*(const short8*)(VsF + (cur << 12) + ((((n) << 4) + l15) << 6) + \
                                      ((((kk) * 4 + lhi) ^ (l15 & 7)) << 3)))
#define EXPST(SV, SUB)                                                         \
    _Pragma("unroll") for (int i = 0; i < 4; ++i) {                            \
        P[wave][lhi * 4 + i][(SUB) * 16 + l15] = f2bf(__expf(SV[i] - 8.f));    \
    }
#define EXPSTM(SV, SUB, QROWB)                                                 \
    _Pragma("unroll") for (int i = 0; i < 4; ++i) {                            \
        float v = SV[i];                                                       \
        if (k0 + (SUB) * 16 + l15 > (QROWB) + i) v = -1e30f;                   \
        P[wave][lhi * 4 + i][(SUB) * 16 + l15] = f2bf(__expf(v - 8.f));        \
    }

    int cur = 0;
    for (int kb = 0; kb < nkb; ++kb) {
        const int k0 = kb << 6;
        if (kb + 1 < nkb) {
            const int kn = k0 + 64;
            const int bo = (cur ^ 1) << 12;
            gload16(&Kp[(size_t)(kn + r0) * 64 + o0], KsF + bo + U0 * 8);
            gload16(&Kp[(size_t)(kn + r1) * 64 + o1], KsF + bo + U1 * 8);
            gload16(&Vp[(size_t)r0 * S_LEN + kn + o0], VsF + bo + U0 * 8);
            gload16(&Vp[(size_t)r1 * S_LEN + kn + o1], VsF + bo + U1 * 8);
        }

        if (kb <= gA) {                    // ---- tile A (block-uniform cond)
            __builtin_amdgcn_s_setprio(1);
            f32x4 s0{}, s1{}, s2{}, s3{};
            s0 = MFMA(aQA0, LDSK(0, 0), s0); s0 = MFMA(aQA1, LDSK(0, 1), s0);
            s1 = MFMA(aQA0, LDSK(1, 0), s1); s1 = MFMA(aQA1, LDSK(1, 1), s1);
            s2 = MFMA(aQA0, LDSK(2, 0), s2); s2 = MFMA(aQA1, LDSK(2, 1), s2);
            s3 = MFMA(aQA0, LDSK(3, 0), s3); s3 = MFMA(aQA1, LDSK(3, 1), s3);
            __builtin_amdgcn_s_setprio(0);
            if (kb == gA) {
                EXPSTM(s0, 0, qrowbA) EXPSTM(s1, 1, qrowbA)
                EXPSTM(s2, 2, qrowbA) EXPSTM(s3, 3, qrowbA)
            } else {
                EXPST(s0, 0) EXPST(s1, 1) EXPST(s2, 2) EXPST(s3, 3)
            }
            short8 aP0 = *(const short8*)&P[wave][l15][lhi * 8];
            short8 aP1 = *(const short8*)&P[wave][l15][32 + lhi * 8];
            __builtin_amdgcn_s_setprio(1);
            ssumA = MFMA(aP0, ones, ssumA); ssumA = MFMA(aP1, ones, ssumA);
            OA0 = MFMA(aP0, LDSV(0, 0), OA0); OA0 = MFMA(aP1, LDSV(0, 1), OA0);
            OA1 = MFMA(aP0, LDSV(1, 0), OA1); OA1 = MFMA(aP1, LDSV(1, 1), OA1);
            OA2 = MFMA(aP0, LDSV(2, 0), OA2); OA2 = MFMA(aP1, LDSV(2, 1), OA2);
            OA3 = MFMA(aP0, LDSV(3, 0), OA3); OA3 = MFMA(aP1, LDSV(3, 1), OA3);
            __builtin_amdgcn_s_setprio(0);
        }

        {                                   // ---- tile B (always active)
            __builtin_amdgcn_s_setprio(1);
            f32x4 s0{}, s1{}, s2{}, s3{};
            s0 = MFMA(aQB0, LDSK(0, 0), s0); s0 = MFMA(aQB1, LDSK(0, 1), s0);
            s1 = MFMA(aQB0, LDSK(1, 0), s1); s1 = MFMA(aQB1, LDSK(1, 1), s1);
            s2 = MFMA(aQB0, LDSK(2, 0), s2); s2 = MFMA(aQB1, LDSK(2, 1), s2);
            s3 = MFMA(aQB0, LDSK(3, 0), s3); s3 = MFMA(aQB1, LDSK(3, 1), s3);
            __builtin_amdgcn_s_setprio(0);
            if (kb == gB) {
                EXPSTM(s0, 0, qrowbB) EXPSTM(s1, 1, qrowbB)
                EXPSTM(s2, 2, qrowbB) EXPSTM(s3, 3, qrowbB)
            } else {
                EXPST(s0, 0) EXPST(s1, 1) EXPST(s2, 2) EXPST(s3, 3)
            }
            short8 aP0 = *(const short8*)&P[wave][l15][lhi * 8];
            short8 aP1 = *(const short8*)&P[wave][l15][32 + lhi * 8];
            __builtin_amdgcn_s_setprio(1);
            ssumB = MFMA(aP0, ones, ssumB); ssumB = MFMA(aP1, ones, ssumB);
            OB0 = MFMA(aP0, LDSV(0, 0), OB0); OB0 = MFMA(aP1, LDSV(0, 1), OB0);
            OB1 = MFMA(aP0, LDSV(1, 0), OB1); OB1 = MFMA(aP1, LDSV(1, 1), OB1);
            OB2 = MFMA(aP0, LDSV(2, 0), OB2); OB2 = MFMA(aP1, LDSV(2, 1), OB2);
            OB3 = MFMA(aP0, LDSV(3, 0), OB3); OB3 = MFMA(aP1, LDSV(3, 1), OB3);
            __builtin_amdgcn_s_setprio(0);
        }

        __syncthreads();
        cur ^= 1;
    }
#undef LDSK
#undef LDSV
#undef EXPST
#undef EXPSTM

#define WOUT(OV, N, QB, INV)                                                   \
    _Pragma("unroll") for (int i = 0; i < 4; ++i) {                            \
        int row = (QB) + lhi * 4 + i;                                          \
        attnB[((size_t)(b * S_LEN + row)) * DM + h * 64 + (N) * 16 + l15] =    \
            f2bf(OV[i] * INV[i]);                                              \
    }
    {
        f32x4 invA, invB;
#pragma unroll
        for (int i = 0; i < 4; ++i) {
            invA[i] = 1.f / ssumA[i];
            invB[i] = 1.f / ssumB[i];
        }
        WOUT(OA0, 0, qbA, invA) WOUT(OA1, 1, qbA, invA)
        WOUT(OA2, 2, qbA, invA) WOUT(OA3, 3, qbA, invA)
        WOUT(OB0, 0, qbB, invB) WOUT(OB1, 1, qbB, invB)
        WOUT(OB2, 2, qbB, invB) WOUT(OB3, 3, qbB, invB)
    }
#undef WOUT
}

// ---------------------------------------------------------------------------
extern "C" void kernel_launch(void* const* d_in, const int* in_sizes, int n_in,
                              void* d_out, int out_size, void* d_ws, size_t ws_size,
                              hipStream_t stream) {
    (void)in_sizes; (void)n_in; (void)out_size; (void)ws_size;
    const float* hs   = (const float*)d_in[0];
    const int*   pos  = (const int*)d_in[1];
    const float* Wqkv = (const float*)d_in[3];
    const float* Wout = (const float*)d_in[4];
    float* out = (float*)d_out;

    char* ws = (char*)d_ws;
    size_t off = 0;
    ushort* hsB   = (ushort*)(ws + off); off += (size_t)4096 * 1024 * 2;   // 8MB
    ushort* WqkvB = (ushort*)(ws + off); off += (size_t)3072 * 1024 * 2;   // 6MB
    ushort* WoutB = (ushort*)(ws + off); off += (size_t)1024 * 1024 * 2;   // 2MB
    ushort* Qh    = (ushort*)(ws + off); off += (size_t)NBH * 1024 * 64 * 2; // 8MB
    ushort* Kh    = (ushort*)(ws + off); off += (size_t)NBH * 1024 * 64 * 2; // 8MB
    ushort* Vt    = (ushort*)(ws + off); off += (size_t)NBH * 64 * 1024 * 2; // 8MB
    ushort* attnB = (ushort*)(ws + off); off += (size_t)4096 * 1024 * 2;   // 8MB
    float*  tab   = (float*)(ws + off);  off += (size_t)4096 * 32 * 2 * 4; // 1MB

    // conversions + RoPE table, one launch (8704 = 8192 cvt + 512 tab blocks)
    k_cvt3<<<8704, 256, 0, stream>>>((const float4*)hs, (const float4*)Wqkv,
                                     (const float4*)Wout, (ushort4*)hsB,
                                     (ushort4*)WqkvB, (ushort4*)WoutB, tab);

    // GEMM1 fused: qkv proj + RoPE + head split + V transpose (128^2 ring)
    k_gemm<1><<<768, 256, 0, stream>>>(hsB, WqkvB, nullptr, pos, tab,
                                       Qh, Kh, Vt, 4096, 3072, 1024, 24);

    // attention: dual q-tile blocks, grid (bh, g)
    k_attn<<<dim3(64, 8), 256, 0, stream>>>(Qh, Kh, Vt, attnB);

    // GEMM2: out projection, f32 output (128^2 ring)
    k_gemm<0><<<256, 256, 0, stream>>>(attnB, WoutB, out, nullptr, nullptr,
                                       nullptr, nullptr, nullptr, 4096, 1024, 1024, 8);
}